// Round 13
// baseline (104.379 us; speedup 1.0000x reference)
//
#include <hip/hip_runtime.h>
#include <hip/hip_bf16.h>
#include <math.h>

typedef __attribute__((ext_vector_type(8))) short bf16x8;
typedef __attribute__((ext_vector_type(4))) float f32x4;
typedef unsigned short u16;

#define L_SEQ 256
#define TMP 16      // pairs per group
#define MFMA __builtin_amdgcn_mfma_f32_16x16x32_bf16

// ws element offsets (u16 elements). Packed B-fragment layout per layer:
// [kt][ct(8)][lane(64)][e(8)], elem = W[kt*32 + (lane>>4)*8 + e][ct*16 + (lane&15)]
#define WS_B1   0        // dist_w1: Kp=256 (K=225), 8 kt
#define WS_B2   32768    // dist_w2: Kp=128, 4 kt
#define WS_B3   49152    // out_w1:  Kp=416 (K=410), 13 kt
#define WS_B4   102400   // out_w2:  Kp=128
#define WS_B5   118784   // out_w3:  Kp=128
#define WS_L4LO 135168   // lo parts, out_w2
#define WS_L5LO 151552   // lo parts, out_w3
#define WS_TOTAL 167936  // u16 elements
#define SP_N    108900   // 484*225 (f32, pre-scaled softplus)
#define WS_EA   385736   // WS_TOTAL + SP_N*2 : bf16 aa_embed  484x128
#define WS_ER   447688   // WS_EA + 61952     : bf16 relpos    66x128 (row 65 = 0)
#define NE_A    61952
#define NE_R    8448

// manual RNE (prep kernels only)
__device__ inline u16 f2bf(float f){
    unsigned u = __float_as_uint(f);
    unsigned r = (u + 0x7FFFu + ((u >> 16) & 1u)) >> 16;
    return (u16)r;
}
// HW RNE via builtin cast (hot kernel)
__device__ inline u16 f2bfq(float f){
    union { __hip_bfloat16 h; u16 u; } c;
    c.h = __float2bfloat16(f);
    return c.u;
}
__device__ inline float bf2f(u16 h){ return __uint_as_float(((unsigned)h) << 16); }

struct F3 { float x, y, z; };
__device__ inline F3 f3sub(F3 a, F3 b){ return {a.x-b.x, a.y-b.y, a.z-b.z}; }
__device__ inline F3 f3cross(F3 a, F3 b){
    return {a.y*b.z - a.z*b.y, a.z*b.x - a.x*b.z, a.x*b.y - a.y*b.x};
}
__device__ inline float f3dot(F3 a, F3 b){ return a.x*b.x + a.y*b.y + a.z*b.z; }

__device__ inline float dihedral(F3 p0, F3 p1, F3 p2, F3 p3){
    F3 v0 = f3sub(p2, p1);
    F3 v1 = f3sub(p0, p1);
    F3 v2 = f3sub(p3, p2);
    F3 u1 = f3cross(v0, v1);
    F3 u2 = f3cross(v0, v2);
    float in1 = rsqrtf(f3dot(u1, u1) + 1e-10f);
    float in2 = rsqrtf(f3dot(u2, u2) + 1e-10f);
    F3 n1 = {u1.x*in1, u1.y*in1, u1.z*in1};
    F3 n2 = {u2.x*in2, u2.y*in2, u2.z*in2};
    float s = f3dot(f3cross(v0, n1), n2);
    float sgn = (s > 0.f) ? 1.f : ((s < 0.f) ? -1.f : 0.f);
    float c = f3dot(n1, n2);
    c = fminf(fmaxf(c, -1.f + 1e-7f), 1.f - 1e-7f);
    return sgn * acosf(c);
}

// ---------------- prep kernels ----------------
__global__ __launch_bounds__(256)
void prep_w(const float* __restrict__ w1, const float* __restrict__ w2,
            const float* __restrict__ w3, const float* __restrict__ w4,
            const float* __restrict__ w5, u16* __restrict__ ws)
{
    int idx = blockIdx.x * 256 + threadIdx.x;
    if (idx >= WS_TOTAL) return;
    const float* W; int Kreal, rel; bool lo = false;
    if      (idx < WS_B2)   { W = w1; Kreal = 225; rel = idx; }
    else if (idx < WS_B3)   { W = w2; Kreal = 128; rel = idx - WS_B2; }
    else if (idx < WS_B4)   { W = w3; Kreal = 410; rel = idx - WS_B3; }
    else if (idx < WS_B5)   { W = w4; Kreal = 128; rel = idx - WS_B4; }
    else if (idx < WS_L4LO) { W = w5; Kreal = 128; rel = idx - WS_B5; }
    else if (idx < WS_L5LO) { W = w4; Kreal = 128; rel = idx - WS_L4LO; lo = true; }
    else                    { W = w5; Kreal = 128; rel = idx - WS_L5LO; lo = true; }
    int e = rel & 7, lane = (rel >> 3) & 63, ct = (rel >> 9) & 7, kt = rel >> 12;
    int k = kt*32 + ((lane >> 4) << 3) + e;
    int col = ct*16 + (lane & 15);
    float v = (k < Kreal) ? W[k*128 + col] : 0.f;
    u16 h = f2bf(v);
    ws[idx] = lo ? f2bf(v - bf2f(h)) : h;
}

__global__ __launch_bounds__(256)
void prep_t(const float* __restrict__ dc, const float* __restrict__ aaw,
            const float* __restrict__ rpw, u16* __restrict__ ws)
{
    int i = blockIdx.x * 256 + threadIdx.x;
    float* sp = (float*)(ws + WS_TOTAL);
    if (i < SP_N){
        float cw = dc[i];
        sp[i] = (fmaxf(cw, 0.f) + log1pf(expf(-fabsf(cw)))) * 0.01f;
    }
    if (i < NE_A) ws[WS_EA + i] = f2bf(aaw[i]);
    if (i < NE_R) ws[WS_ER + i] = (i >> 7) < 65 ? f2bf(rpw[i]) : (u16)0;
}

// ---------------- dual-group single-ct MFMA gemm (R8/R9/R10-proven) ----------------
template<int T, bool SWZ>
__device__ inline void gemm16d(const u16* __restrict__ A0, const u16* __restrict__ A1,
                               int lda, const u16* __restrict__ B,
                               int ct, int lane, f32x4 acc[2])
{
    const int r15 = lane & 15;
    const int koff = (lane >> 4) << 3;
    const int sx = SWZ ? ((r15 & 7) << 3) : 0;
    const u16* a0p = A0 + r15*lda;
    const u16* a1p = A1 + r15*lda;
#pragma unroll
    for (int kt = 0; kt < T; ++kt){
        int kk = ((kt << 5) + koff) ^ sx;
        bf16x8 a0 = *(const bf16x8*)(a0p + kk);
        bf16x8 a1 = *(const bf16x8*)(a1p + kk);
        bf16x8 b  = *(const bf16x8*)(B + (((kt*8 + ct)*64 + lane) << 3));
        acc[0] = MFMA(a0, b, acc[0], 0, 0, 0);
        acc[1] = MFMA(a1, b, acc[1], 0, 0, 0);
    }
}

template<int T>
__device__ inline void gemm16ds(const u16* __restrict__ Ah0, const u16* __restrict__ Al0,
                                const u16* __restrict__ Ah1, const u16* __restrict__ Al1,
                                int lda, const u16* __restrict__ Bh, const u16* __restrict__ Bl,
                                int ct, int lane, f32x4 acc[2])
{
    const int r15 = lane & 15;
    const int koff = (lane >> 4) << 3;
    const int sx = (r15 & 7) << 3;
#pragma unroll
    for (int kt = 0; kt < T; ++kt){
        int kk = ((kt << 5) + koff) ^ sx;
        bf16x8 ah0 = *(const bf16x8*)(Ah0 + r15*lda + kk);
        bf16x8 al0 = *(const bf16x8*)(Al0 + r15*lda + kk);
        bf16x8 ah1 = *(const bf16x8*)(Ah1 + r15*lda + kk);
        bf16x8 al1 = *(const bf16x8*)(Al1 + r15*lda + kk);
        const int bo = ((kt*8 + ct)*64 + lane) << 3;
        bf16x8 bh = *(const bf16x8*)(Bh + bo);
        bf16x8 bl = *(const bf16x8*)(Bl + bo);
        acc[0] = MFMA(ah0, bh, acc[0], 0, 0, 0);
        acc[0] = MFMA(ah0, bl, acc[0], 0, 0, 0);
        acc[0] = MFMA(al0, bh, acc[0], 0, 0, 0);
        acc[1] = MFMA(ah1, bh, acc[1], 0, 0, 0);
        acc[1] = MFMA(ah1, bl, acc[1], 0, 0, 0);
        acc[1] = MFMA(al1, bh, acc[1], 0, 0, 0);
    }
}

// epilogue (proven C/D mapping; converts via HW cvt)
__device__ inline void epi16d(f32x4 acc[2], const float* __restrict__ bias,
                              int ct, int lane,
                              u16* D0hi, u16* D0lo, u16* D1hi, u16* D1lo)
{
    const int rr = (lane >> 4) << 2;
    const int col = ct*16 + (lane & 15);
    const float b = bias[col];
#pragma unroll
    for (int r = 0; r < 4; ++r){
        int m = rr + r;
        int idx = m*128 + (col ^ ((m & 7) << 3));
        float v0 = fmaxf(acc[0][r] + b, 0.f);
        float v1 = fmaxf(acc[1][r] + b, 0.f);
        u16 h0 = f2bfq(v0), h1 = f2bfq(v1);
        D0hi[idx] = h0;
        D1hi[idx] = h1;
        if (D0lo) D0lo[idx] = f2bfq(v0 - bf2f(h0));
        if (D1lo) D1lo[idx] = f2bfq(v1 - bf2f(h1));
    }
}

// ---------------- main fused kernel ----------------
__global__ __launch_bounds__(512, 6)
void rpe_mfma7(const int* __restrict__ aa, const int* __restrict__ res_nb,
               const int* __restrict__ chain_nb,
               const float* __restrict__ pos_atoms, const float* __restrict__ mask_atoms,
               const float* __restrict__ dist_b1, const float* __restrict__ dist_b2,
               const float* __restrict__ out_b1, const float* __restrict__ out_b2,
               const float* __restrict__ out_b3,
               const u16* __restrict__ ws, float* __restrict__ out)
{
    const int t  = threadIdx.x;
    const int g  = t >> 8;          // feature-phase group 0/1
    const int tl = t & 255;
    const int bid = blockIdx.x;     // 0..4095
    const int n  = bid >> 11;
    const int i  = (bid >> 3) & 255;
    const int j0b = (bid & 7) << 5; // block j-base (32 pairs)
    const int j0 = j0b + g*16;
    const int ri = n*L_SEQ + i;
    const int rj0 = n*L_SEQ + j0;

    __shared__ __align__(16) u16 s_g[2][TMP*264];    // gauss, lda 264 | L3+: h3h @0, h3l @2048 (lda128 swz)
    __shared__ __align__(16) u16 s_c1[2][TMP*264];   // aapair|relpos | L4+: h4h @0, h4l @2048
    __shared__ __align__(16) u16 s_c2[2][TMP*128];   // dist feat (XOR swz)
    __shared__ __align__(16) u16 s_c3[2][TMP*32];    // dihed, plain lda 32 (26 + pad)
    __shared__ __align__(16) u16 s_h1s[2][TMP*128];  // h1 (XOR swz); ALIASED with float4 staging
    __shared__ int   s_aapE[2][TMP];   // aap*256  (byte row offset, bf16 aa table)
    __shared__ int   s_aapS[2][TMP];   // aap*225  (f32 element row offset, sp table)
    __shared__ int   s_rpE[2][TMP];    // (same? rp:65)*256 byte row offset
    __shared__ float s_mpair[2][TMP];

    const float* sp_table = (const float*)(ws + WS_TOTAL);

    // float4 staging in dead h1 region: [16 res][15 atoms] {x,y,z,mask} + [15] for residue i
    float4* u_pm4  = (float4*)s_h1s[g];      // 240 * 16B = 3840 B
    float4* u_pmi4 = u_pm4 + 240;            // 15  * 16B -> total 4080 <= 4096 B

    // ---- stage residue data (per group), packed float4 ----
    if (tl < 240){
        int base = rj0*45 + tl*3;            // tl = m*15 + b  ->  m*45 + b*3 = 3*tl
        u_pm4[tl] = make_float4(pos_atoms[base], pos_atoms[base+1], pos_atoms[base+2],
                                mask_atoms[rj0*15 + tl]);
    } else if (tl < 255){
        int b = tl - 240;
        int base = ri*45 + b*3;
        u_pmi4[b] = make_float4(pos_atoms[base], pos_atoms[base+1], pos_atoms[base+2],
                                mask_atoms[ri*15 + b]);
    }
    if (tl < TMP){
        int m = tl, rj = rj0 + m;
        int aap = aa[ri]*22 + aa[rj];
        s_aapE[g][m] = aap << 8;        // *256 B
        s_aapS[g][m] = aap * 225;       // f32 elements
        int d = res_nb[ri] - res_nb[rj];
        d = min(max(d, -32), 32);
        bool same = (chain_nb[ri] == chain_nb[rj]);
        s_rpE[g][m] = (same ? (d + 32) : 65) << 8;
    }
    __syncthreads();   // B1: staging complete

    if (tl < TMP) s_mpair[g][tl] = u_pmi4[1].w * u_pm4[tl*15 + 1].w;   // BB_CA = 1

    // ---- gaussian distance features: k = tl fixed per thread, one b128 read per m ----
    {
        const int kg = tl;
        const bool act = kg < 225;
        if (act){
            int ga = kg / 15, gb = kg - ga*15;
            float4 pi = u_pmi4[ga];
#pragma unroll 4
            for (int m = 0; m < TMP; ++m){
                float4 pj = u_pm4[m*15 + gb];
                float dx = pi.x - pj.x;
                float dy = pi.y - pj.y;
                float dz = pi.z - pj.z;
                float d2 = fmaf(dz, dz, fmaf(dy, dy, fmaf(dx, dx, 1e-10f)));
                float c  = sp_table[s_aapS[g][m] + kg];          // already *0.01
                float gv = expf(-c*d2) * (pi.w * pj.w);
                s_g[g][m*264 + kg] = f2bfq(gv);
            }
        } else {
#pragma unroll
            for (int m = 0; m < TMP; ++m) s_g[g][m*264 + kg] = 0;   // zero cols 225..255
        }
    }

    // ---- embedding gathers: pure 16B copies from pre-converted bf16 tables ----
    {
        const u16* EA = ws + WS_EA;
        const u16* ER = ws + WS_ER;
#pragma unroll
        for (int it = 0; it < 2; ++it){
            int cid = tl + it*256;            // 0..511
            int m = cid >> 5, ch = cid & 31;  // 32 chunks of 8 u16 per row
            const u16* src = (ch < 16)
                ? (const u16*)((const char*)EA + s_aapE[g][m] + (ch << 4))
                : (const u16*)((const char*)ER + s_rpE[g][m] + ((ch - 16) << 4));
            *(bf16x8*)(s_c1[g] + m*264 + (ch << 3)) = *(const bf16x8*)src;
        }
    }

    // ---- dihedral features (plain lda-32 store) ----
    if (tl < 2*TMP){
        int m = tl >> 1, w = tl & 1;
        F3 P0, P1, P2, P3;
        float4 q0, q1, q2, q3;
        if (w == 0){   // phi: pC_i, pN_j, pCA_j, pC_j
            q0 = u_pmi4[2];       q1 = u_pm4[m*15 + 0];
            q2 = u_pm4[m*15 + 1]; q3 = u_pm4[m*15 + 2];
        } else {       // psi: pN_i, pCA_i, pC_i, pN_j
            q0 = u_pmi4[0];       q1 = u_pmi4[1];
            q2 = u_pmi4[2];       q3 = u_pm4[m*15 + 0];
        }
        P0 = {q0.x, q0.y, q0.z}; P1 = {q1.x, q1.y, q1.z};
        P2 = {q2.x, q2.y, q2.z}; P3 = {q3.x, q3.y, q3.z};
        float x = dihedral(P0, P1, P2, P3);
        u16* c3 = s_c3[g] + m*32 + w*13;
        c3[0]  = f2bfq(x);
        c3[1]  = f2bfq(sinf(x));
        c3[2]  = f2bfq(sinf(2.f*x));
        c3[3]  = f2bfq(sinf(3.f*x));
        c3[4]  = f2bfq(sinf(x));
        c3[5]  = f2bfq(sinf(0.5f*x));
        c3[6]  = f2bfq(sinf(x*(1.f/3.f)));
        c3[7]  = f2bfq(cosf(x));
        c3[8]  = f2bfq(cosf(2.f*x));
        c3[9]  = f2bfq(cosf(3.f*x));
        c3[10] = f2bfq(cosf(x));
        c3[11] = f2bfq(cosf(0.5f*x));
        c3[12] = f2bfq(cosf(x*(1.f/3.f)));
    }
    if (tl < TMP*6){ int m = tl/6; s_c3[g][m*32 + 26 + tl - m*6] = 0; }   // pad cols 26..31
    __syncthreads();   // B2: features complete (incl. all staging reads)

    const int lane = t & 63;
    const int w = t >> 6;          // wave -> ONE ct index (0..7), both groups

    u16* h3h0 = s_g[0];   u16* h3l0 = s_g[0]  + 2048;
    u16* h3h1 = s_g[1];   u16* h3l1 = s_g[1]  + 2048;
    u16* h4h0 = s_c1[0];  u16* h4l0 = s_c1[0] + 2048;
    u16* h4h1 = s_c1[1];  u16* h4l1 = s_c1[1] + 2048;

    // ---- L1: h1 = relu(g @ W1 + b1) ----
    f32x4 acc[2];
    acc[0] = {0,0,0,0}; acc[1] = {0,0,0,0};
    gemm16d<8,false>(s_g[0], s_g[1], 264, ws + WS_B1, w, lane, acc);
    epi16d(acc, dist_b1, w, lane, s_h1s[0], nullptr, s_h1s[1], nullptr);  // overwrites dead staging
    __syncthreads();   // B3

    // ---- L2: feat_dist = relu(h1 @ W2 + b2) ----
    acc[0] = {0,0,0,0}; acc[1] = {0,0,0,0};
    gemm16d<4,true>(s_h1s[0], s_h1s[1], 128, ws + WS_B2, w, lane, acc);
    epi16d(acc, dist_b2, w, lane, s_c2[0], nullptr, s_c2[1], nullptr);
    __syncthreads();   // B4

    // ---- L3: h3 = relu([c1|c2|c3] @ W3 + b3) -> hi+lo (aliases s_g) ----
    acc[0] = {0,0,0,0}; acc[1] = {0,0,0,0};
    gemm16d<8,false>(s_c1[0], s_c1[1], 264, ws + WS_B3,           w, lane, acc);
    gemm16d<4,true >(s_c2[0], s_c2[1], 128, ws + WS_B3 +  8*4096, w, lane, acc);
    gemm16d<1,false>(s_c3[0], s_c3[1],  32, ws + WS_B3 + 12*4096, w, lane, acc);
    epi16d(acc, out_b1, w, lane, h3h0, h3l0, h3h1, h3l1);
    __syncthreads();   // B5

    // ---- L4: h4 = relu(h3 @ W4 + b4) (split; aliases s_c1) ----
    acc[0] = {0,0,0,0}; acc[1] = {0,0,0,0};
    gemm16ds<4>(h3h0, h3l0, h3h1, h3l1, 128, ws + WS_B4, ws + WS_L4LO, w, lane, acc);
    epi16d(acc, out_b2, w, lane, h4h0, h4l0, h4h1, h4l1);
    __syncthreads();   // B6

    // ---- L5: out = (h4 @ W5 + b5) * mask_pair (split) ----
    acc[0] = {0,0,0,0}; acc[1] = {0,0,0,0};
    gemm16ds<4>(h4h0, h4l0, h4h1, h4l1, 128, ws + WS_B5, ws + WS_L5LO, w, lane, acc);
    {
        const int rr = (lane >> 4) << 2;
        const int col = w*16 + (lane & 15);
        const float b = out_b3[col];
#pragma unroll
        for (int gg = 0; gg < 2; ++gg){
            int jg = j0b + gg*16;
#pragma unroll
            for (int r = 0; r < 4; ++r){
                int m = rr + r;
                out[((size_t)(ri*L_SEQ) + (size_t)(jg + m))*128 + col] = (acc[gg][r] + b) * s_mpair[gg][m];
            }
        }
    }
}

extern "C" void kernel_launch(void* const* d_in, const int* in_sizes, int n_in,
                              void* d_out, int out_size, void* d_ws, size_t ws_size,
                              hipStream_t stream) {
    const int*   aa             = (const int*)  d_in[0];
    const int*   res_nb         = (const int*)  d_in[1];
    const int*   chain_nb       = (const int*)  d_in[2];
    const float* pos_atoms      = (const float*)d_in[3];
    const float* mask_atoms     = (const float*)d_in[4];
    const float* aa_embed_w     = (const float*)d_in[5];
    const float* relpos_embed_w = (const float*)d_in[6];
    const float* distcoef_w     = (const float*)d_in[7];
    const float* dist_w1        = (const float*)d_in[8];
    const float* dist_b1        = (const float*)d_in[9];
    const float* dist_w2        = (const float*)d_in[10];
    const float* dist_b2        = (const float*)d_in[11];
    const float* out_w1         = (const float*)d_in[12];
    const float* out_b1         = (const float*)d_in[13];
    const float* out_w2         = (const float*)d_in[14];
    const float* out_b2         = (const float*)d_in[15];
    const float* out_w3         = (const float*)d_in[16];
    const float* out_b3         = (const float*)d_in[17];
    float* out = (float*)d_out;
    u16* ws = (u16*)d_ws;

    hipLaunchKernelGGL(prep_w, dim3((WS_TOTAL + 255)/256), dim3(256), 0, stream,
                       dist_w1, dist_w2, out_w1, out_w2, out_w3, ws);
    hipLaunchKernelGGL(prep_t, dim3((SP_N + 255)/256), dim3(256), 0, stream,
                       distcoef_w, aa_embed_w, relpos_embed_w, ws);

    const int nblocks = 2 * L_SEQ * (L_SEQ / 32);   // 4096
    hipLaunchKernelGGL(rpe_mfma7, dim3(nblocks), dim3(512), 0, stream,
                       aa, res_nb, chain_nb, pos_atoms, mask_atoms,
                       dist_b1, dist_b2, out_b1, out_b2, out_b3,
                       ws, out);
}